// Round 2
// baseline (2735.352 us; speedup 1.0000x reference)
//
#include <hip/hip_runtime.h>

// LSTM: B=32, S=2048, I=H=256. Reference dtype = float32 for ALL tensors.
// d_in: 0=x,1=Wf,2=Uf,3=bf,4=Wi,5=Ui,6=bi,7=Wo,8=Uo,9=bo,10=Wc,11=Uc,12=bc
// gate concat order in z: [f, i, c(g), o]
// d_out (float): hidden_seq [32][2048][256], h_t @16777216, c_t @16785408
//
// Pipeline: prep (W->bf16 WT transposed, U->int8 qUT per-col quant)
//           per time-chunk: proj (x@W bf16 MFMA -> xg bf16) ; rec (persistent
//           8-block recurrence, U int8 resident in VGPRs, h int8 via LDS).
// ws layout: WT 512K | qUT 256K | scales 4K | qcarry 8K | ccarry 32K | xg chunk

typedef int    v4i  __attribute__((ext_vector_type(4)));
typedef float  v4f  __attribute__((ext_vector_type(4)));
typedef __bf16 v8bf __attribute__((ext_vector_type(8)));

#define LOG2E 1.442695040888963f

__device__ __forceinline__ float fast_sigmoid(float x) {
    return __builtin_amdgcn_rcpf(1.f + __builtin_amdgcn_exp2f(-LOG2E * x));
}
__device__ __forceinline__ float fast_tanh(float x) {
    return 1.f - 2.f * __builtin_amdgcn_rcpf(__builtin_amdgcn_exp2f(2.f * LOG2E * x) + 1.f);
}

// ---------------- K1: prep WT (bf16) and qUT (int8) + scales ----------------
// grid 2048 x 64. Blocks 0..1023: WT row n (= W column n). 1024..2047: qUT.
__global__ void prep_kernel(
    const float* __restrict__ Wf, const float* __restrict__ Wi,
    const float* __restrict__ Wc, const float* __restrict__ Wo,
    const float* __restrict__ Uf, const float* __restrict__ Ui,
    const float* __restrict__ Uc, const float* __restrict__ Uo,
    __bf16* __restrict__ WT, signed char* __restrict__ qUT,
    float* __restrict__ scales)
{
    int n = blockIdx.x;
    int lane = threadIdx.x;  // 0..63
    if (n < 1024) {
        const float* src = (n < 256) ? Wf : (n < 512) ? Wi : (n < 768) ? Wc : Wo;
        int c = n & 255;
        #pragma unroll
        for (int q = 0; q < 4; ++q) {
            int k = q * 64 + lane;
            WT[n * 256 + k] = (__bf16)src[k * 256 + c];
        }
    } else {
        int nn = n - 1024;
        const float* src = (nn < 256) ? Uf : (nn < 512) ? Ui : (nn < 768) ? Uc : Uo;
        int c = nn & 255;
        float v[4];
        float m = 0.f;
        #pragma unroll
        for (int q = 0; q < 4; ++q) {
            v[q] = src[(q * 64 + lane) * 256 + c];
            m = fmaxf(m, fabsf(v[q]));
        }
        #pragma unroll
        for (int s = 1; s < 64; s <<= 1) m = fmaxf(m, __shfl_xor(m, s));
        float inv = (m > 1e-20f) ? (127.f / m) : 0.f;
        #pragma unroll
        for (int q = 0; q < 4; ++q) {
            int qq = (int)__builtin_rintf(v[q] * inv);
            qUT[nn * 256 + q * 64 + lane] = (signed char)qq;
        }
        if (lane == 0) scales[nn] = m / 16129.f;  // m/(127*127)
    }
}

// ---------------- K2: xg = x @ [Wf Wi Wc Wo] + b  (bf16 out, chunk-local) --
// grid (8, Tc/2), 256 thr. Block: 64 xg-rows x 128 cols. xg row = t*32+b.
__global__ __launch_bounds__(256) void proj_kernel(
    const float* __restrict__ x, const __bf16* __restrict__ WT,
    const float* __restrict__ bf_, const float* __restrict__ bi_,
    const float* __restrict__ bc_, const float* __restrict__ bo_,
    __bf16* __restrict__ xg, int t0)
{
    int tid = threadIdx.x;
    int lane = tid & 63, wid = tid >> 6;
    int quad = lane >> 4, l16 = lane & 15;
    int bx = blockIdx.x;   // N block (128 cols)
    int by = blockIdx.y;   // M block (64 rows, chunk-local)

    int lr = by * 64 + wid * 16 + l16;   // chunk-local xg row for A
    int r = t0 * 32 + lr;                // global row = t*32 + b
    int bb = r & 31, tt = r >> 5;
    const float* xrow = x + (bb * 2048 + tt) * 256;

    v4f acc[8] = {};
    #pragma unroll
    for (int kt = 0; kt < 8; ++kt) {
        int k = kt * 32 + quad * 8;
        v4f a0 = *(const v4f*)(xrow + k);
        v4f a1 = *(const v4f*)(xrow + k + 4);
        v8bf af;
        #pragma unroll
        for (int j = 0; j < 4; ++j) { af[j] = (__bf16)a0[j]; af[4 + j] = (__bf16)a1[j]; }
        #pragma unroll
        for (int nt = 0; nt < 8; ++nt) {
            int n = bx * 128 + nt * 16 + l16;
            v8bf bfr = *(const v8bf*)(WT + n * 256 + k);
            acc[nt] = __builtin_amdgcn_mfma_f32_16x16x32_bf16(af, bfr, acc[nt], 0, 0, 0);
        }
    }
    #pragma unroll
    for (int nt = 0; nt < 8; ++nt) {
        int n = bx * 128 + nt * 16 + l16;
        const float* bsrc = (n < 256) ? bf_ : (n < 512) ? bi_ : (n < 768) ? bc_ : bo_;
        float bias = bsrc[n & 255];
        #pragma unroll
        for (int rg = 0; rg < 4; ++rg) {
            int lrow = by * 64 + wid * 16 + quad * 4 + rg;   // chunk-local
            xg[lrow * 1024 + n] = (__bf16)(acc[nt][rg] + bias);
        }
    }
}

// ---------------- K3: persistent recurrence, 8 blocks x 512 threads --------
// Block owns batches b0..b0+3 at MFMA A-rows {0,4,8,12} (=> acc reg 0).
// U int8 resident in VGPRs. h round-trips via int8 LDS. c fp32 in regs.
__global__ __launch_bounds__(512, 2) void lstm_rec_kernel(
    const __bf16* __restrict__ xg,       // chunk: [Tc*32][1024] bf16
    const signed char* __restrict__ qUT, // [1024][256]
    const float* __restrict__ scales,    // [1024]
    float* __restrict__ out,
    int t0, int Tc,
    signed char* __restrict__ qcarry,    // [32][256] int8 h carry
    float* __restrict__ ccarry)          // [32][256] f32 c carry
{
    __shared__ __align__(16) signed char qh[16 * 272];
    __shared__ __align__(16) unsigned char xbuf[2][4 * 2064];

    const int tid = threadIdx.x;
    const int lane = tid & 63, wid = tid >> 6;   // 8 waves
    const int quad = lane >> 4, l16 = lane & 15;
    const int b0 = blockIdx.x * 4;

    // persistent B-frags (U int8) + scales
    v4i bfr[8][4];
    float scl[8];
    int jcol[8];
    #pragma unroll
    for (int g = 0; g < 4; ++g) {
        #pragma unroll
        for (int jh = 0; jh < 2; ++jh) {
            int tl = g * 2 + jh;
            int n = g * 256 + wid * 32 + jh * 16 + l16;
            jcol[tl] = n;
            scl[tl] = scales[n];
            #pragma unroll
            for (int kt = 0; kt < 4; ++kt)
                bfr[tl][kt] = *(const v4i*)(qUT + n * 256 + kt * 64 + quad * 16);
        }
    }

    // zero q_h (unused rows stay zero forever)
    for (int i = tid; i < (16 * 272) / 4; i += 512) ((int*)qh)[i] = 0;
    __syncthreads();

    float c0 = 0.f, c1 = 0.f;
    if (t0 != 0) {
        int j0 = wid * 32 + l16;
        qh[quad * 4 * 272 + j0]      = qcarry[(b0 + quad) * 256 + j0];
        qh[quad * 4 * 272 + j0 + 16] = qcarry[(b0 + quad) * 256 + j0 + 16];
        c0 = ccarry[(b0 + quad) * 256 + j0];
        c1 = ccarry[(b0 + quad) * 256 + j0 + 16];
    }

    // prefetch xg chunk-row block 0
    const char* xgb = (const char*)xg;
    {
        v4i st = *(const v4i*)(xgb + (0 * 32 + b0) * 2048 + tid * 16);
        int p = tid >> 7, off = (tid * 16) & 2047;
        *(v4i*)(xbuf[0] + p * 2064 + off) = st;
    }
    __syncthreads();

    for (int tl_ = 0; tl_ < Tc; ++tl_) {
        const int t = t0 + tl_;
        const unsigned char* xb = xbuf[tl_ & 1];

        v4i a[4];
        #pragma unroll
        for (int kt = 0; kt < 4; ++kt)
            a[kt] = *(const v4i*)(qh + l16 * 272 + kt * 64 + quad * 16);
        float xv[8];
        #pragma unroll
        for (int g = 0; g < 8; ++g)
            xv[g] = (float)(*(const __bf16*)(xb + quad * 2064 + jcol[g] * 2));

        __syncthreads();  // barrier1: q_h/xbuf reads done

        v4i nst;
        if (tl_ < Tc - 1)
            nst = *(const v4i*)(xgb + ((tl_ + 1) * 32 + b0) * 2048 + tid * 16);

        v4i acc[8];
        #pragma unroll
        for (int g = 0; g < 8; ++g) acc[g] = (v4i){0, 0, 0, 0};
        #pragma unroll
        for (int kt = 0; kt < 4; ++kt) {
            #pragma unroll
            for (int g = 0; g < 8; ++g)
                acc[g] = __builtin_amdgcn_mfma_i32_16x16x64_i8(a[kt], bfr[g][kt], acc[g], 0, 0, 0);
        }

        // pointwise: only acc reg 0 (rows {0,4,8,12}) is real; batch = quad
        #pragma unroll
        for (int jh = 0; jh < 2; ++jh) {
            float zf = xv[0 + jh] + scl[0 + jh] * (float)acc[0 + jh][0];
            float zi = xv[2 + jh] + scl[2 + jh] * (float)acc[2 + jh][0];
            float zg = xv[4 + jh] + scl[4 + jh] * (float)acc[4 + jh][0];
            float zo = xv[6 + jh] + scl[6 + jh] * (float)acc[6 + jh][0];
            float f  = fast_sigmoid(zf);
            float i_ = fast_sigmoid(zi);
            float g_ = fast_tanh(zg);
            float o_ = fast_sigmoid(zo);
            float c = (jh == 0) ? c0 : c1;
            c = f * c + i_ * g_;
            if (jh == 0) c0 = c; else c1 = c;
            float h = o_ * fast_tanh(c);

            int j = wid * 32 + jh * 16 + l16;
            int q = (int)__builtin_rintf(h * 127.f);
            qh[quad * 4 * 272 + j] = (signed char)q;
            out[((b0 + quad) * 2048 + t) * 256 + j] = h;
            if (t == 2047) {
                out[16777216 + (b0 + quad) * 256 + j] = h;
                out[16785408 + (b0 + quad) * 256 + j] = c;
            }
            if (tl_ == Tc - 1) {
                qcarry[(b0 + quad) * 256 + j] = (signed char)q;
                ccarry[(b0 + quad) * 256 + j] = c;
            }
        }

        if (tl_ < Tc - 1) {
            int p = tid >> 7, off = (tid * 16) & 2047;
            *(v4i*)(xbuf[(tl_ + 1) & 1] + p * 2064 + off) = nst;
        }
        __syncthreads();  // barrier2: q_h[t+1] + xbuf[t+1] visible
    }
}

extern "C" void kernel_launch(void* const* d_in, const int* in_sizes, int n_in,
                              void* d_out, int out_size, void* d_ws, size_t ws_size,
                              hipStream_t stream) {
    const float* x   = (const float*)d_in[0];
    const float* Wf  = (const float*)d_in[1];
    const float* Uf  = (const float*)d_in[2];
    const float* bf_ = (const float*)d_in[3];
    const float* Wi  = (const float*)d_in[4];
    const float* Ui  = (const float*)d_in[5];
    const float* bi_ = (const float*)d_in[6];
    const float* Wo  = (const float*)d_in[7];
    const float* Uo  = (const float*)d_in[8];
    const float* bo_ = (const float*)d_in[9];
    const float* Wc  = (const float*)d_in[10];
    const float* Uc  = (const float*)d_in[11];
    const float* bc_ = (const float*)d_in[12];

    char* ws = (char*)d_ws;
    __bf16*      WT     = (__bf16*)ws;                    // 524288 B
    signed char* qUT    = (signed char*)(ws + 524288);    // 262144 B
    float*       scales = (float*)(ws + 786432);          //   4096 B
    signed char* qcarry = (signed char*)(ws + 790528);    //   8192 B
    float*       ccarry = (float*)(ws + 798720);          //  32768 B
    __bf16*      xg     = (__bf16*)(ws + 831488);         // Tc*65536 B

    size_t avail = (ws_size > 831488) ? ws_size - 831488 : 0;
    int Tc = 2048;
    while (Tc > 2 && (size_t)Tc * 65536ULL > avail) Tc >>= 1;

    prep_kernel<<<dim3(2048), dim3(64), 0, stream>>>(
        Wf, Wi, Wc, Wo, Uf, Ui, Uc, Uo, WT, qUT, scales);
    for (int t0 = 0; t0 < 2048; t0 += Tc) {
        proj_kernel<<<dim3(8, Tc / 2), dim3(256), 0, stream>>>(
            x, WT, bf_, bi_, bc_, bo_, xg, t0);
        lstm_rec_kernel<<<dim3(8), dim3(512), 0, stream>>>(
            xg, qUT, scales, (float*)d_out, t0, Tc, qcarry, ccarry);
    }
}

// Round 3
// 2352.179 us; speedup vs baseline: 1.1629x; 1.1629x over previous
//
#include <hip/hip_runtime.h>

// LSTM: B=32, S=2048, I=H=256. All global tensors float32.
// d_in: 0=x,1=Wf,2=Uf,3=bf,4=Wi,5=Ui,6=bi,7=Wo,8=Uo,9=bo,10=Wc,11=Uc,12=bc
// d_out (float): hidden_seq [32][2048][256], h_t @16777216, c_t @16785408
//
// rec kernel structure (per CU): ONE barrier/step, qh ping-pong, xg streamed
// through a 4-slot LDS ring via global_load_lds (prefetch distance 3),
// out stores batched 4 steps. U int8 resident in VGPRs.

typedef int    v4i  __attribute__((ext_vector_type(4)));
typedef float  v4f  __attribute__((ext_vector_type(4)));
typedef __bf16 v8bf __attribute__((ext_vector_type(8)));

#define LOG2E 1.442695040888963f

__device__ __forceinline__ float fast_sigmoid(float x) {
    return __builtin_amdgcn_rcpf(1.f + __builtin_amdgcn_exp2f(-LOG2E * x));
}
__device__ __forceinline__ float fast_tanh(float x) {
    return 1.f - 2.f * __builtin_amdgcn_rcpf(__builtin_amdgcn_exp2f(2.f * LOG2E * x) + 1.f);
}

__device__ __forceinline__ void async_copy16(const void* g, void* l) {
    __builtin_amdgcn_global_load_lds(
        (const __attribute__((address_space(1))) unsigned int*)g,
        (__attribute__((address_space(3))) unsigned int*)l, 16, 0, 0);
}

// ---------------- K1: prep WT (bf16) and qUT (int8) + scales ----------------
__global__ void prep_kernel(
    const float* __restrict__ Wf, const float* __restrict__ Wi,
    const float* __restrict__ Wc, const float* __restrict__ Wo,
    const float* __restrict__ Uf, const float* __restrict__ Ui,
    const float* __restrict__ Uc, const float* __restrict__ Uo,
    __bf16* __restrict__ WT, signed char* __restrict__ qUT,
    float* __restrict__ scales)
{
    int n = blockIdx.x;
    int lane = threadIdx.x;  // 0..63
    if (n < 1024) {
        const float* src = (n < 256) ? Wf : (n < 512) ? Wi : (n < 768) ? Wc : Wo;
        int c = n & 255;
        #pragma unroll
        for (int q = 0; q < 4; ++q) {
            int k = q * 64 + lane;
            WT[n * 256 + k] = (__bf16)src[k * 256 + c];
        }
    } else {
        int nn = n - 1024;
        const float* src = (nn < 256) ? Uf : (nn < 512) ? Ui : (nn < 768) ? Uc : Uo;
        int c = nn & 255;
        float v[4];
        float m = 0.f;
        #pragma unroll
        for (int q = 0; q < 4; ++q) {
            v[q] = src[(q * 64 + lane) * 256 + c];
            m = fmaxf(m, fabsf(v[q]));
        }
        #pragma unroll
        for (int s = 1; s < 64; s <<= 1) m = fmaxf(m, __shfl_xor(m, s));
        float inv = (m > 1e-20f) ? (127.f / m) : 0.f;
        #pragma unroll
        for (int q = 0; q < 4; ++q) {
            int qq = (int)__builtin_rintf(v[q] * inv);
            qUT[nn * 256 + q * 64 + lane] = (signed char)qq;
        }
        if (lane == 0) scales[nn] = m / 16129.f;  // m/(127*127)
    }
}

// ---------------- K2: xg = x @ [Wf Wi Wc Wo] + b (bf16, chunk-local rows) --
__global__ __launch_bounds__(256) void proj_kernel(
    const float* __restrict__ x, const __bf16* __restrict__ WT,
    const float* __restrict__ bf_, const float* __restrict__ bi_,
    const float* __restrict__ bc_, const float* __restrict__ bo_,
    __bf16* __restrict__ xg, int t0)
{
    int tid = threadIdx.x;
    int lane = tid & 63, wid = tid >> 6;
    int quad = lane >> 4, l16 = lane & 15;
    int bx = blockIdx.x;   // N block (128 cols)
    int by = blockIdx.y;   // M block (64 rows, chunk-local)

    int lr = by * 64 + wid * 16 + l16;
    int r = t0 * 32 + lr;
    int bb = r & 31, tt = r >> 5;
    const float* xrow = x + (bb * 2048 + tt) * 256;

    v4f acc[8] = {};
    #pragma unroll
    for (int kt = 0; kt < 8; ++kt) {
        int k = kt * 32 + quad * 8;
        v4f a0 = *(const v4f*)(xrow + k);
        v4f a1 = *(const v4f*)(xrow + k + 4);
        v8bf af;
        #pragma unroll
        for (int j = 0; j < 4; ++j) { af[j] = (__bf16)a0[j]; af[4 + j] = (__bf16)a1[j]; }
        #pragma unroll
        for (int nt = 0; nt < 8; ++nt) {
            int n = bx * 128 + nt * 16 + l16;
            v8bf bfr = *(const v8bf*)(WT + n * 256 + k);
            acc[nt] = __builtin_amdgcn_mfma_f32_16x16x32_bf16(af, bfr, acc[nt], 0, 0, 0);
        }
    }
    #pragma unroll
    for (int nt = 0; nt < 8; ++nt) {
        int n = bx * 128 + nt * 16 + l16;
        const float* bsrc = (n < 256) ? bf_ : (n < 512) ? bi_ : (n < 768) ? bc_ : bo_;
        float bias = bsrc[n & 255];
        #pragma unroll
        for (int rg = 0; rg < 4; ++rg) {
            int lrow = by * 64 + wid * 16 + quad * 4 + rg;
            xg[lrow * 1024 + n] = (__bf16)(acc[nt][rg] + bias);
        }
    }
}

// ---------------- K3: persistent recurrence, 8 blocks x 512 threads --------
#define SLOT 8320    // 4 batch-rows, padded stride 2080 (2048 data)
#define QHB  1152    // one qh buffer: 4 batches x 288 (stride/16 = 18 == 2 mod 8)

__global__ __launch_bounds__(512, 2) void lstm_rec_kernel(
    const __bf16* __restrict__ xg,       // chunk: [Tc*32][1024] bf16
    const signed char* __restrict__ qUT, // [1024][256]
    const float* __restrict__ scales,    // [1024]
    float* __restrict__ out,
    int t0, int Tc,
    signed char* __restrict__ qcarry,    // [32][256]
    float* __restrict__ ccarry)          // [32][256]
{
    __shared__ __align__(16) char ring[4 * SLOT];        // 33280 B
    __shared__ __align__(16) signed char qh[2 * QHB];    //  2304 B

    const int tid = threadIdx.x;
    const int lane = tid & 63, wid = tid >> 6;   // 8 waves
    const int quad = lane >> 4, l16 = lane & 15;
    const int b0 = blockIdx.x * 4;
    const bool arow = (l16 & 3) == 0;            // lanes holding real A rows
    const int bq = l16 >> 2;

    // persistent B-frags (U int8) + scales
    v4i bfr[8][4];
    float scl[8];
    int jcol[8];
    #pragma unroll
    for (int g = 0; g < 4; ++g) {
        #pragma unroll
        for (int jh = 0; jh < 2; ++jh) {
            int tl = g * 2 + jh;
            int n = g * 256 + wid * 32 + jh * 16 + l16;
            jcol[tl] = n;
            scl[tl] = scales[n];
            #pragma unroll
            for (int kt = 0; kt < 4; ++kt)
                bfr[tl][kt] = *(const v4i*)(qUT + n * 256 + kt * 64 + quad * 16);
        }
    }

    // zero both qh buffers
    for (int i = tid; i < (2 * QHB) / 4; i += 512) ((int*)qh)[i] = 0;
    __syncthreads();

    float c0 = 0.f, c1 = 0.f;
    const int j0 = wid * 32 + l16;
    if (t0 != 0) {
        qh[quad * 288 + j0]      = qcarry[(b0 + quad) * 256 + j0];
        qh[quad * 288 + j0 + 16] = qcarry[(b0 + quad) * 256 + j0 + 16];
        c0 = ccarry[(b0 + quad) * 256 + j0];
        c1 = ccarry[(b0 + quad) * 256 + j0 + 16];
    }

    // preload ring slots 0..2 (each wave: 1 KB per slot)
    const char* xgb = (const char*)xg;
    const int wrow = wid >> 1, whalf = wid & 1;
    #pragma unroll
    for (int s = 0; s < 3; ++s) {
        if (s < Tc) {
            long src = ((long)(s * 32 + b0 + wrow)) * 2048 + whalf * 1024 + (long)lane * 16;
            char* dst = ring + s * SLOT + wrow * 2080 + whalf * 1024;
            async_copy16(xgb + src, dst);
        }
    }

    float* orow = out + ((long)(b0 + quad)) * 2048 * 256 + j0;
    float hreg[4][2];

    for (int tl4 = 0; tl4 < Tc; tl4 += 4) {
        #pragma unroll
        for (int u = 0; u < 4; ++u) {
            const int tl = tl4 + u;
            const int t = t0 + tl;

            __syncthreads();  // qh[(tl)&1] writes + ring slot (tl&3) visible

            // prefetch xg for step tl+3 into slot (u+3)&3
            if (tl + 3 < Tc) {
                long src = ((long)((tl + 3) * 32 + b0 + wrow)) * 2048 + whalf * 1024 + (long)lane * 16;
                char* dst = ring + ((u + 3) & 3) * SLOT + wrow * 2080 + whalf * 1024;
                async_copy16(xgb + src, dst);
            }

            const signed char* qA = qh + (u & 1) * QHB;
            signed char* qB = qh + ((u + 1) & 1) * QHB;
            const char* xb = ring + (u & 3) * SLOT + quad * 2080;

            // A-frags: only 16 lanes read LDS, rest are zero rows
            v4i a[4];
            #pragma unroll
            for (int kt = 0; kt < 4; ++kt) {
                v4i z = (v4i){0, 0, 0, 0};
                a[kt] = arow ? *(const v4i*)(qA + bq * 288 + kt * 64 + quad * 16) : z;
            }
            float xv[8];
            #pragma unroll
            for (int g = 0; g < 8; ++g)
                xv[g] = (float)(*(const __bf16*)(xb + jcol[g] * 2));

            v4i acc[8];
            #pragma unroll
            for (int g = 0; g < 8; ++g) acc[g] = (v4i){0, 0, 0, 0};
            #pragma unroll
            for (int kt = 0; kt < 4; ++kt) {
                #pragma unroll
                for (int g = 0; g < 8; ++g)
                    acc[g] = __builtin_amdgcn_mfma_i32_16x16x64_i8(a[kt], bfr[g][kt], acc[g], 0, 0, 0);
            }

            // pointwise: acc reg 0 = rows {0,4,8,12}; batch = quad
            #pragma unroll
            for (int jh = 0; jh < 2; ++jh) {
                float zf = xv[0 + jh] + scl[0 + jh] * (float)acc[0 + jh][0];
                float zi = xv[2 + jh] + scl[2 + jh] * (float)acc[2 + jh][0];
                float zg = xv[4 + jh] + scl[4 + jh] * (float)acc[4 + jh][0];
                float zo = xv[6 + jh] + scl[6 + jh] * (float)acc[6 + jh][0];
                float f  = fast_sigmoid(zf);
                float i_ = fast_sigmoid(zi);
                float g_ = fast_tanh(zg);
                float o_ = fast_sigmoid(zo);
                float c = (jh == 0) ? c0 : c1;
                c = f * c + i_ * g_;
                if (jh == 0) c0 = c; else c1 = c;
                float h = o_ * fast_tanh(c);
                hreg[u][jh] = h;

                int j = j0 + jh * 16;
                int q = (int)__builtin_rintf(h * 127.f);
                qB[quad * 288 + j] = (signed char)q;
                if (t == 2047) {
                    out[16777216 + (b0 + quad) * 256 + j] = h;
                    out[16785408 + (b0 + quad) * 256 + j] = c;
                }
                if (tl == Tc - 1) {
                    qcarry[(b0 + quad) * 256 + j] = (signed char)q;
                    ccarry[(b0 + quad) * 256 + j] = c;
                }
            }

            // flush 4 steps of h to global (drains once per 4 steps)
            if (u == 3) {
                #pragma unroll
                for (int s = 0; s < 4; ++s) {
                    long ts = t - 3 + s;
                    orow[ts * 256]      = hreg[s][0];
                    orow[ts * 256 + 16] = hreg[s][1];
                }
            }
        }
    }
}

extern "C" void kernel_launch(void* const* d_in, const int* in_sizes, int n_in,
                              void* d_out, int out_size, void* d_ws, size_t ws_size,
                              hipStream_t stream) {
    const float* x   = (const float*)d_in[0];
    const float* Wf  = (const float*)d_in[1];
    const float* Uf  = (const float*)d_in[2];
    const float* bf_ = (const float*)d_in[3];
    const float* Wi  = (const float*)d_in[4];
    const float* Ui  = (const float*)d_in[5];
    const float* bi_ = (const float*)d_in[6];
    const float* Wo  = (const float*)d_in[7];
    const float* Uo  = (const float*)d_in[8];
    const float* bo_ = (const float*)d_in[9];
    const float* Wc  = (const float*)d_in[10];
    const float* Uc  = (const float*)d_in[11];
    const float* bc_ = (const float*)d_in[12];

    char* ws = (char*)d_ws;
    __bf16*      WT     = (__bf16*)ws;                    // 524288 B
    signed char* qUT    = (signed char*)(ws + 524288);    // 262144 B
    float*       scales = (float*)(ws + 786432);          //   4096 B
    signed char* qcarry = (signed char*)(ws + 790528);    //   8192 B
    float*       ccarry = (float*)(ws + 798720);          //  32768 B
    __bf16*      xg     = (__bf16*)(ws + 831488);         // Tc*65536 B

    size_t avail = (ws_size > 831488) ? ws_size - 831488 : 0;
    int Tc = 2048;
    while (Tc > 8 && (size_t)Tc * 65536ULL > avail) Tc >>= 1;

    prep_kernel<<<dim3(2048), dim3(64), 0, stream>>>(
        Wf, Wi, Wc, Wo, Uf, Ui, Uc, Uo, WT, qUT, scales);
    for (int t0 = 0; t0 < 2048; t0 += Tc) {
        proj_kernel<<<dim3(8, Tc / 2), dim3(256), 0, stream>>>(
            x, WT, bf_, bi_, bc_, bo_, xg, t0);
        lstm_rec_kernel<<<dim3(8), dim3(512), 0, stream>>>(
            xg, qUT, scales, (float*)d_out, t0, Tc, qcarry, ccarry);
    }
}

// Round 4
// 1998.871 us; speedup vs baseline: 1.3684x; 1.1768x over previous
//
#include <hip/hip_runtime.h>

// LSTM: B=32, S=2048, I=H=256. All global tensors float32.
// d_in: 0=x,1=Wf,2=Uf,3=bf,4=Wi,5=Ui,6=bi,7=Wo,8=Uo,9=bo,10=Wc,11=Uc,12=bc
// d_out (float): hidden_seq [32][2048][256], h_t @16777216, c_t @16785408
//
// rec: 8 persistent blocks x 1024 threads (16 waves, 4/SIMD for MFMA/VALU
// overlap). Each wave owns hidden slice j in [16w,16w+16) x all 4 gates
// (16 MFMA/step). U int8 in VGPRs. xg streamed via global_load_lds ring,
// gate-interleaved layout (col' = j*4+g) so xv is one ds_read_b64.
// No A-row masking: MFMA D-rows outside {0,4,8,12} are garbage-by-design.

typedef int    v4i  __attribute__((ext_vector_type(4)));
typedef float  v4f  __attribute__((ext_vector_type(4)));
typedef __bf16 v8bf __attribute__((ext_vector_type(8)));
typedef __bf16 v4bf __attribute__((ext_vector_type(4)));

#define LOG2E 1.442695040888963f

__device__ __forceinline__ float fast_sigmoid(float x) {
    return __builtin_amdgcn_rcpf(1.f + __builtin_amdgcn_exp2f(-LOG2E * x));
}
__device__ __forceinline__ float fast_tanh(float x) {
    return 1.f - 2.f * __builtin_amdgcn_rcpf(__builtin_amdgcn_exp2f(2.f * LOG2E * x) + 1.f);
}

__device__ __forceinline__ void async_copy16(const void* g, void* l) {
    __builtin_amdgcn_global_load_lds(
        (const __attribute__((address_space(1))) unsigned int*)g,
        (__attribute__((address_space(3))) unsigned int*)l, 16, 0, 0);
}

// ---------------- K1: prep WT (bf16) and qUT (int8) + scales ----------------
__global__ void prep_kernel(
    const float* __restrict__ Wf, const float* __restrict__ Wi,
    const float* __restrict__ Wc, const float* __restrict__ Wo,
    const float* __restrict__ Uf, const float* __restrict__ Ui,
    const float* __restrict__ Uc, const float* __restrict__ Uo,
    __bf16* __restrict__ WT, signed char* __restrict__ qUT,
    float* __restrict__ scales)
{
    int n = blockIdx.x;
    int lane = threadIdx.x;  // 0..63
    if (n < 1024) {
        const float* src = (n < 256) ? Wf : (n < 512) ? Wi : (n < 768) ? Wc : Wo;
        int c = n & 255;
        #pragma unroll
        for (int q = 0; q < 4; ++q) {
            int k = q * 64 + lane;
            WT[n * 256 + k] = (__bf16)src[k * 256 + c];
        }
    } else {
        int nn = n - 1024;
        const float* src = (nn < 256) ? Uf : (nn < 512) ? Ui : (nn < 768) ? Uc : Uo;
        int c = nn & 255;
        float v[4];
        float m = 0.f;
        #pragma unroll
        for (int q = 0; q < 4; ++q) {
            v[q] = src[(q * 64 + lane) * 256 + c];
            m = fmaxf(m, fabsf(v[q]));
        }
        #pragma unroll
        for (int s = 1; s < 64; s <<= 1) m = fmaxf(m, __shfl_xor(m, s));
        float inv = (m > 1e-20f) ? (127.f / m) : 0.f;
        #pragma unroll
        for (int q = 0; q < 4; ++q) {
            int qq = (int)__builtin_rintf(v[q] * inv);
            qUT[nn * 256 + q * 64 + lane] = (signed char)qq;
        }
        if (lane == 0) scales[nn] = m / 16129.f;  // m/(127*127)
    }
}

// ---------------- K2: xg = x @ [W] + b, gate-interleaved bf16 out ----------
// grid (Tc/2), 256 thr. Block: 64 rows x ALL 1024 cols; x staged in LDS once.
// Output layout: xg[row][j*4+g]  (j=hidden 0..255, g=gate f,i,c,o).
__global__ __launch_bounds__(256) void proj_kernel(
    const float* __restrict__ x, const __bf16* __restrict__ WT,
    const float* __restrict__ bf_, const float* __restrict__ bi_,
    const float* __restrict__ bc_, const float* __restrict__ bo_,
    __bf16* __restrict__ xg, int t0)
{
    __shared__ __align__(16) __bf16 xs[64][264];   // 264 = 256 + 8 pad

    int tid = threadIdx.x;
    int lane = tid & 63, wid = tid >> 6;
    int quad = lane >> 4, l16 = lane & 15;
    int by = blockIdx.x;

    // stage x rows (f32 -> bf16) into LDS: thread = (row, 64-col segment)
    {
        int row = tid >> 2, seg = (tid & 3) * 64;
        int r = t0 * 32 + by * 64 + row;
        int bb = r & 31, tt = r >> 5;
        const float* xrow = x + ((long)(bb * 2048 + tt)) * 256 + seg;
        #pragma unroll
        for (int q = 0; q < 16; ++q) {
            v4f v = *(const v4f*)(xrow + q * 4);
            v4bf o;
            #pragma unroll
            for (int j = 0; j < 4; ++j) o[j] = (__bf16)v[j];
            *(v4bf*)(&xs[row][seg + q * 4]) = o;
        }
    }
    __syncthreads();

    // A-frags once (persist across all 8 N-panels)
    v8bf af[8];
    #pragma unroll
    for (int kt = 0; kt < 8; ++kt)
        af[kt] = *(const v8bf*)(&xs[wid * 16 + l16][kt * 32 + quad * 8]);

    #pragma unroll
    for (int p = 0; p < 8; ++p) {
        v4f acc[8] = {};
        #pragma unroll
        for (int kt = 0; kt < 8; ++kt) {
            int k = kt * 32 + quad * 8;
            #pragma unroll
            for (int nt = 0; nt < 8; ++nt) {
                int n = p * 128 + nt * 16 + l16;
                v8bf bfr = *(const v8bf*)(WT + n * 256 + k);
                acc[nt] = __builtin_amdgcn_mfma_f32_16x16x32_bf16(af[kt], bfr, acc[nt], 0, 0, 0);
            }
        }
        #pragma unroll
        for (int nt = 0; nt < 8; ++nt) {
            int n = p * 128 + nt * 16 + l16;
            const float* bsrc = (n < 256) ? bf_ : (n < 512) ? bi_ : (n < 768) ? bc_ : bo_;
            float bias = bsrc[n & 255];
            int colp = (n & 255) * 4 + (n >> 8);   // gate-interleaved
            #pragma unroll
            for (int rg = 0; rg < 4; ++rg) {
                int lrow = by * 64 + wid * 16 + quad * 4 + rg;
                xg[(long)lrow * 1024 + colp] = (__bf16)(acc[nt][rg] + bias);
            }
        }
    }
}

// ---------------- K3: persistent recurrence, 8 blocks x 1024 threads -------
#define SLOT 8320    // 4 batch-rows, padded stride 2080 (2048 B data each)
#define QHB  1152    // one qh buffer: 4 batches x 288

__global__ __launch_bounds__(1024) void lstm_rec_kernel(
    const __bf16* __restrict__ xg,       // chunk: [Tc*32][1024] gate-interleaved
    const signed char* __restrict__ qUT, // [1024][256]
    const float* __restrict__ scales,    // [1024]
    float* __restrict__ out,
    int t0, int Tc,
    signed char* __restrict__ qcarry,    // [32][256]
    float* __restrict__ ccarry)          // [32][256]
{
    __shared__ __align__(16) char ring[4 * SLOT];        // 33280 B
    __shared__ __align__(16) signed char qh[2 * QHB];    //  2304 B

    const int tid = threadIdx.x;
    const int lane = tid & 63, wid = tid >> 6;   // 16 waves
    const int quad = lane >> 4, l16 = lane & 15;
    const int b0 = blockIdx.x * 4;
    const int j = wid * 16 + l16;                // hidden index 0..255

    // persistent B-frags: all 4 gates for hidden col j
    v4i bfr[4][4];
    float scl[4];
    #pragma unroll
    for (int g = 0; g < 4; ++g) {
        int n = g * 256 + j;
        scl[g] = scales[n];
        #pragma unroll
        for (int kt = 0; kt < 4; ++kt)
            bfr[g][kt] = *(const v4i*)(qUT + n * 256 + kt * 64 + quad * 16);
    }

    // zero both qh buffers
    if (tid < (2 * QHB) / 4) ((int*)qh)[tid] = 0;
    __syncthreads();

    float c = 0.f;
    if (t0 != 0) {
        qh[quad * 288 + j] = qcarry[(b0 + quad) * 256 + j];
        c = ccarry[(b0 + quad) * 256 + j];
    }

    // preload ring slots 0..2 (waves 0..7 only: 512 lanes x 16 B = 8 KB/slot)
    const char* xgb = (const char*)xg;
    const int wrow = wid >> 1, whalf = wid & 1;
    if (tid < 512) {
        #pragma unroll
        for (int s = 0; s < 3; ++s) {
            if (s < Tc) {
                long src = ((long)(s * 32 + b0 + wrow)) * 2048 + whalf * 1024 + (long)lane * 16;
                char* dst = ring + s * SLOT + wrow * 2080 + whalf * 1024;
                async_copy16(xgb + src, dst);
            }
        }
    }

    float* orow = out + ((long)(b0 + quad)) * 2048 * 256 + j;
    float hreg[4];

    for (int tl4 = 0; tl4 < Tc; tl4 += 4) {
        #pragma unroll
        for (int u = 0; u < 4; ++u) {
            const int tl = tl4 + u;
            const int t = t0 + tl;

            __syncthreads();  // qh[(tl)&1] writes + ring slot (tl&3) visible

            // prefetch xg for step tl+3 into slot (u+3)&3
            if (tid < 512 && tl + 3 < Tc) {
                long src = ((long)((tl + 3) * 32 + b0 + wrow)) * 2048 + whalf * 1024 + (long)lane * 16;
                char* dst = ring + ((u + 3) & 3) * SLOT + wrow * 2080 + whalf * 1024;
                async_copy16(xgb + src, dst);
            }

            const signed char* qA = qh + (u & 1) * QHB;
            signed char* qB = qh + ((u + 1) & 1) * QHB;
            const char* xb = ring + (u & 3) * SLOT + quad * 2080;

            // A-frags: every lane reads (rows outside {0,4,8,12} give garbage
            // D-rows we never read — no masking needed)
            v4i a[4];
            #pragma unroll
            for (int kt = 0; kt < 4; ++kt)
                a[kt] = *(const v4i*)(qA + (l16 >> 2) * 288 + kt * 64 + quad * 16);

            // 4 gate pre-activations for (batch=quad, hidden=j): one b64 read
            v4bf xp = *(const v4bf*)(xb + j * 8);

            v4i acc[4];
            #pragma unroll
            for (int g = 0; g < 4; ++g) acc[g] = (v4i){0, 0, 0, 0};
            #pragma unroll
            for (int kt = 0; kt < 4; ++kt) {
                #pragma unroll
                for (int g = 0; g < 4; ++g)
                    acc[g] = __builtin_amdgcn_mfma_i32_16x16x64_i8(a[kt], bfr[g][kt], acc[g], 0, 0, 0);
            }

            // pointwise: one h per lane (batch=quad, hidden=j)
            float zf = (float)xp[0] + scl[0] * (float)acc[0][0];
            float zi = (float)xp[1] + scl[1] * (float)acc[1][0];
            float zg = (float)xp[2] + scl[2] * (float)acc[2][0];
            float zo = (float)xp[3] + scl[3] * (float)acc[3][0];
            float f  = fast_sigmoid(zf);
            float i_ = fast_sigmoid(zi);
            float g_ = fast_tanh(zg);
            float o_ = fast_sigmoid(zo);
            c = f * c + i_ * g_;
            float h = o_ * fast_tanh(c);
            hreg[u] = h;

            int q = (int)__builtin_rintf(h * 127.f);
            qB[quad * 288 + j] = (signed char)q;
            if (t == 2047) {
                out[16777216 + (b0 + quad) * 256 + j] = h;
                out[16785408 + (b0 + quad) * 256 + j] = c;
            }
            if (tl == Tc - 1) {
                qcarry[(b0 + quad) * 256 + j] = (signed char)q;
                ccarry[(b0 + quad) * 256 + j] = c;
            }
        }

        // flush 4 steps of h (store-drain amortized over 4 barriers)
        {
            long tb = (long)(t0 + tl4) * 256;
            #pragma unroll
            for (int s = 0; s < 4; ++s)
                orow[tb + s * 256] = hreg[s];
        }
    }
}

extern "C" void kernel_launch(void* const* d_in, const int* in_sizes, int n_in,
                              void* d_out, int out_size, void* d_ws, size_t ws_size,
                              hipStream_t stream) {
    const float* x   = (const float*)d_in[0];
    const float* Wf  = (const float*)d_in[1];
    const float* Uf  = (const float*)d_in[2];
    const float* bf_ = (const float*)d_in[3];
    const float* Wi  = (const float*)d_in[4];
    const float* Ui  = (const float*)d_in[5];
    const float* bi_ = (const float*)d_in[6];
    const float* Wo  = (const float*)d_in[7];
    const float* Uo  = (const float*)d_in[8];
    const float* bo_ = (const float*)d_in[9];
    const float* Wc  = (const float*)d_in[10];
    const float* Uc  = (const float*)d_in[11];
    const float* bc_ = (const float*)d_in[12];

    char* ws = (char*)d_ws;
    __bf16*      WT     = (__bf16*)ws;                    // 524288 B
    signed char* qUT    = (signed char*)(ws + 524288);    // 262144 B
    float*       scales = (float*)(ws + 786432);          //   4096 B
    signed char* qcarry = (signed char*)(ws + 790528);    //   8192 B
    float*       ccarry = (float*)(ws + 798720);          //  32768 B
    __bf16*      xg     = (__bf16*)(ws + 831488);         // Tc*65536 B

    size_t avail = (ws_size > 831488) ? ws_size - 831488 : 0;
    int Tc = 2048;
    while (Tc > 8 && (size_t)Tc * 65536ULL > avail) Tc >>= 1;

    prep_kernel<<<dim3(2048), dim3(64), 0, stream>>>(
        Wf, Wi, Wc, Wo, Uf, Ui, Uc, Uo, WT, qUT, scales);
    for (int t0 = 0; t0 < 2048; t0 += Tc) {
        proj_kernel<<<dim3(Tc / 2), dim3(256), 0, stream>>>(
            x, WT, bf_, bi_, bc_, bo_, xg, t0);
        lstm_rec_kernel<<<dim3(8), dim3(1024), 0, stream>>>(
            xg, qUT, scales, (float*)d_out, t0, Tc, qcarry, ccarry);
    }
}